// Round 11
// baseline (282.512 us; speedup 1.0000x reference)
//
#include <hip/hip_runtime.h>
#include <cstddef>

#define NN   30000
#define NNP  30016          /* NN ints rounded to 256B alloc granularity */
#define NE   240000
#define D1   512
#define D2   128
#define NCLS 20
#define CAP  64             /* padded-CSR slots per node; Poisson(8) tail @64 ~ 1e-38 */
#define NPI  (NN / 4)       /* nodes per gat iteration (7500); 4 iters/wave */
#define GB   (NPI / 4)      /* 1875 persistent gat blocks, 4 waves each */
#define BGRID 2048          /* persistent k_build blocks */
#define CAST_TOT 1025536          /* x(960000) + 4 weights(16384 ea), float4 units */
#define IDG_TOT  (CAST_TOT + NE)  /* + one thread per edge for CSR-build atomics */

typedef __attribute__((ext_vector_type(8))) short short8;
typedef __attribute__((ext_vector_type(4))) float f32x4;
typedef __attribute__((ext_vector_type(2))) float f32x2;

__device__ __forceinline__ unsigned short f2b(float f) {
  union { float f; unsigned int u; } c; c.f = f;
  unsigned int r = (c.u + 0x7fff + ((c.u >> 16) & 1)) >> 16;  // RNE
  return (unsigned short)r;
}
__device__ __forceinline__ float b2f(unsigned short u) {
  union { unsigned int u; float f; } c; c.u = (unsigned int)u << 16;
  return c.f;
}
// two packed bf16 (little-endian: low half = even channel) -> f32x2
__device__ __forceinline__ f32x2 bpair(unsigned int t) {
  f32x2 r;
  r.x = __uint_as_float(t << 16);
  r.y = __uint_as_float(t & 0xffff0000u);
  return r;
}

// ---------------------------------------------------------------- cast + padded-CSR build
// R11: persistent grid-stride (BGRID blocks dispatched once; each thread loops
// over ~3 items). Rationale: block throughput across the whole app pins at
// ~117 wg/us (R4/R6/R8 evidence) -> the 4944-wg version had a ~42us dispatch
// floor. Same per-item body; atomics unchanged (order nondeterministic, same
// class as all prior rounds, absmax stable).
__global__ __launch_bounds__(256) void k_build(
    const float* __restrict__ x,
    const float* __restrict__ Wl1, const float* __restrict__ Wr1,
    const float* __restrict__ Wl2, const float* __restrict__ Wr2,
    const int* __restrict__ src, const int* __restrict__ dst,
    const float* __restrict__ eattr,
    int* __restrict__ cnti,
    int2* __restrict__ se,
    unsigned short* __restrict__ xb,
    unsigned short* __restrict__ Wc1, unsigned short* __restrict__ Wc2) {
  for (int i = blockIdx.x * 256 + threadIdx.x; i < IDG_TOT; i += BGRID * 256) {
    if (i >= CAST_TOT) {               // CSR build atomics
      int e = i - CAST_TOT;
      int d = dst[e];
      int pos = atomicAdd(&cnti[d], 1);
      if (pos < CAP) se[(size_t)d * CAP + pos] = make_int2(src[e], __float_as_int(eattr[e]));
      continue;
    }
    const float* in; unsigned short* outp; int off;
    if      (i <  960000) { in = x;   outp = xb;          off = i; }
    else if (i <  976384) { in = Wl1; outp = Wc1;         off = i -  960000; }
    else if (i <  992768) { in = Wr1; outp = Wc1 + 65536; off = i -  976384; }
    else if (i < 1009152) { in = Wl2; outp = Wc2;         off = i -  992768; }
    else                  { in = Wr2; outp = Wc2 + 65536; off = i - 1009152; }
    float4 v = ((const float4*)in)[off];
    ushort4 o;
    o.x = f2b(v.x); o.y = f2b(v.y); o.z = f2b(v.z); o.w = f2b(v.w);
    ((ushort4*)outp)[off] = o;
  }
}

// ---------------------------------------------------------------- bf16 MFMA GEMM
// [Cl|Cr][m,n] = sum_k A[m,k]*W[n,k] + bias, W = [Wl;Wr] concat in n; split out.
// m97-style staging: UNPADDED LDS, global_load_lds width=16. BK=64 both layers
// (R10's BK=128 regressed +16.6us: 64KB LDS halves resident blocks and kills
// cross-block overlap — m132 replicated. Do not revisit).
// R9 epilogue: LDS-staged vectorized C-write (reuses staging LDS after the
// final barrier; padded stride BN+8): short8 stores, 4 rows x 256B per
// wave-store vs the old 2B scalar scatter. Requires BN | Nhalf (128|512,
// 128|128). No OOB row guard on loads (reads past M land in later workspace
// buffers); the store masks rows >= M.
template <int BN, int NT, int BK>   // NT = BN/32 n-tiles per wave
__global__ __launch_bounds__(256) void gemm_mfma(
    const unsigned short* __restrict__ A, const unsigned short* __restrict__ W,
    const float* __restrict__ bl, const float* __restrict__ br, int Nhalf,
    unsigned short* __restrict__ Cl, unsigned short* __restrict__ Cr,
    int M, int N, int K) {
  constexpr int BM = 128, LDK = BK;    // unpadded (global_load_lds)
  constexpr int RPI = 512 / BK;        // rows per wave per load issue (8@64)
  constexpr int LPR = BK / 8;          // lanes per row (8@64)
  constexpr int CPAD = BN + 8;         // C-stage stride (16B-aligned rows)
  constexpr int SM_STAGE = BM * LDK + BN * LDK;
  constexpr int SM_C = BM * CPAD;
  constexpr int SMEM = SM_STAGE > SM_C ? SM_STAGE : SM_C;
  __shared__ __align__(16) unsigned short smem[SMEM];
  unsigned short* As = smem;
  unsigned short* Bs = smem + BM * LDK;
  const int bm = blockIdx.y * BM;
  const int bn = blockIdx.x * BN;
  const int tid = threadIdx.x;
  const int lane = tid & 63;
  const int wid = __builtin_amdgcn_readfirstlane(tid >> 6);  // wave-uniform (SGPR)
  const int wm = (wid >> 1) * 64;
  const int wn = (wid & 1) * (NT * 16);
  const int l16 = lane & 15, lq = lane >> 4;
  const int lrow = lane / LPR;         // staging: row within RPI
  const int lcol = (lane % LPR) * 8;   // staging: k-offset (8 bf16 = 16 B)

  f32x4 acc[4][NT];
#pragma unroll
  for (int i = 0; i < 4; ++i)
#pragma unroll
    for (int j = 0; j < NT; ++j) acc[i][j] = (f32x4){0.f, 0.f, 0.f, 0.f};

  for (int k0 = 0; k0 < K; k0 += BK) {
#pragma unroll
    for (int p = 0; p < BM / (4 * RPI); ++p) {
      int r = p * (4 * RPI) + wid * RPI;
      const unsigned short* gp = A + (size_t)(bm + r + lrow) * K + k0 + lcol;
      __builtin_amdgcn_global_load_lds(
          (const __attribute__((address_space(1))) unsigned int*)gp,
          (__attribute__((address_space(3))) unsigned int*)(As + (size_t)r * LDK),
          16, 0, 0);
    }
#pragma unroll
    for (int p = 0; p < BN / (4 * RPI); ++p) {
      int r = p * (4 * RPI) + wid * RPI;
      const unsigned short* gp = W + (size_t)(bn + r + lrow) * K + k0 + lcol;
      __builtin_amdgcn_global_load_lds(
          (const __attribute__((address_space(1))) unsigned int*)gp,
          (__attribute__((address_space(3))) unsigned int*)(Bs + (size_t)r * LDK),
          16, 0, 0);
    }
    __syncthreads();
#pragma unroll
    for (int kh = 0; kh < BK / 32; ++kh) {
      short8 af[4], bfr[NT];
#pragma unroll
      for (int mt = 0; mt < 4; ++mt)
        af[mt] = *(const short8*)&As[(wm + mt * 16 + l16) * LDK + kh * 32 + lq * 8];
#pragma unroll
      for (int nt = 0; nt < NT; ++nt)
        bfr[nt] = *(const short8*)&Bs[(wn + nt * 16 + l16) * LDK + kh * 32 + lq * 8];
#pragma unroll
      for (int mt = 0; mt < 4; ++mt)
#pragma unroll
        for (int nt = 0; nt < NT; ++nt)
          acc[mt][nt] = __builtin_amdgcn_mfma_f32_16x16x32_bf16(
              af[mt], bfr[nt], acc[mt][nt], 0, 0, 0);
    }
    __syncthreads();
  }
  // K-loop ended with a barrier: safe to reuse smem as the C-stage.
  unsigned short* Cs = smem;           // [BM][CPAD]
  const bool left = bn < Nhalf;        // block-uniform (BN | Nhalf)
  const int ccb = left ? bn : bn - Nhalf;
  const float* bptr = left ? bl : br;
  unsigned short* Cp = left ? Cl : Cr;

#pragma unroll
  for (int nt = 0; nt < NT; ++nt) {
    int lc = wn + nt * 16 + l16;
    float b = bptr[ccb + lc];
#pragma unroll
    for (int mt = 0; mt < 4; ++mt)
#pragma unroll
      for (int r = 0; r < 4; ++r)
        Cs[(wm + mt * 16 + lq * 4 + r) * CPAD + lc] = f2b(acc[mt][nt][r] + b);
  }
  __syncthreads();
  constexpr int CHR = BN / 8;                  // 16B chunks per row
  constexpr int NPASS = BM * CHR / 256;        // chunks per thread
#pragma unroll
  for (int p = 0; p < NPASS; ++p) {
    int c = p * 256 + tid;
    int row = c / CHR, col8 = (c % CHR) * 8;
    if (bm + row < M)
      *(short8*)&Cp[(size_t)(bm + row) * Nhalf + ccb + col8] =
          *(const short8*)&Cs[row * CPAD + col8];
  }
}

// ---------------------------------------------------------------- fused GATv2 aggregate
// R11: PERSISTENT. GB=1875 blocks x 4 waves dispatched ONCE; each wave
// processes exactly 4 nodes (n = it*NPI + blockIdx*4 + w; NN divides exactly,
// no masking). Rationale: block throughput pins at ~117 wg/us regardless of
// kernel (R4/R6/R8), so the 7500-wg version was dispatch-floor-bound at
// ~60us; persistence decouples residency from CP rate. Inner per-node code
// identical to R9 (EPC chunks, packed f32x2 VOP3P, in-kernel la, per-chunk se
// broadcast load — R7's readlane rewrite regressed). we2/at2 hoisted.
// HEAD_GEMM epilogue barrier-bracketed; all waves run the same 4 iterations.
// Keep VGPR <= 64 (R1: >64 halves wave cap; R5: min-waves clamp caused spills).
template <int D, int EPC, bool DO_SILU, bool OBF, bool HEAD_GEMM>
__global__ __launch_bounds__(256) void k_gat_node(
    const int2* __restrict__ se,
    const int* __restrict__ cnti,
    const unsigned short* __restrict__ xl, const unsigned short* __restrict__ xr,
    const float* __restrict__ We, const float* __restrict__ att,
    const float* __restrict__ bias, const float* __restrict__ w_ln,
    const float* __restrict__ Wout,
    unsigned short* __restrict__ outb, float* __restrict__ outf) {
  constexpr int VEC = D / 64;      // channels per lane (8 for D1, 2 for D2)
  constexpr int PAIRS = VEC / 2;   // f32x2 pairs per lane
  const int w = __builtin_amdgcn_readfirstlane(threadIdx.x) >> 6;  // SGPR wave id
  const int lane = threadIdx.x & 63;
  const int c0 = lane * VEC;
  const int nb = blockIdx.x * 4 + w;              // SGPR base slot

  f32x2 we2[PAIRS], at2[PAIRS];                   // node-independent: hoisted
  {
    const f32x2* Wep = (const f32x2*)(We + c0);
    const f32x2* atp = (const f32x2*)(att + c0);
#pragma unroll
    for (int i = 0; i < PAIRS; i++) { we2[i] = Wep[i]; at2[i] = atp[i]; }
  }

  __shared__ __align__(16) float hrow[4][D2];

  for (int it = 0; it < 4; ++it) {
    const int n = it * NPI + nb;                  // SGPR node

    f32x2 xd2[PAIRS], acc2[PAIRS];
    {
      unsigned int tr[PAIRS];
      if constexpr (PAIRS == 4) {
        uint4 t = *(const uint4*)(xr + (size_t)n * D + c0);
        tr[0] = t.x; tr[1] = t.y; tr[2] = t.z; tr[3] = t.w;
      } else {
        tr[0] = *(const unsigned int*)(xr + (size_t)n * D + c0);
      }
#pragma unroll
      for (int i = 0; i < PAIRS; i++) {
        xd2[i] = bpair(tr[i]);
        acc2[i] = (f32x2){0.f, 0.f};
      }
    }

    const int start = n * CAP;
    const int deg = cnti[n];
    float denom = 0.f;
    float easum = 0.f;
    const int nfullE = deg / EPC;                 // full chunks of EDGES only

    // shared chunk body; wgt==nullptr folds the mask away at the full-chunk site
    auto body = [&](const int (&s)[EPC], const float (&eav)[EPC], const float* wgt) {
      unsigned int uu[EPC][PAIRS];
#pragma unroll
      for (int k = 0; k < EPC; k++) {              // EPC gathers in flight
        if constexpr (PAIRS == 4) {
          uint4 t = *(const uint4*)(xl + (size_t)s[k] * D + c0);
          uu[k][0] = t.x; uu[k][1] = t.y; uu[k][2] = t.z; uu[k][3] = t.w;
        } else {
          uu[k][0] = *(const unsigned int*)(xl + (size_t)s[k] * D + c0);
        }
      }
      f32x2 xs2[EPC][PAIRS];
      f32x2 p2[EPC];
#pragma unroll
      for (int j = 0; j < EPC; j++) p2[j] = (f32x2){0.f, 0.f};
#pragma unroll
      for (int i = 0; i < PAIRS; i++) {
#pragma unroll
        for (int j = 0; j < EPC; j++) {
          f32x2 xs = bpair(uu[j][i]);
          xs2[j][i] = xs;
          f32x2 ea = {eav[j], eav[j]};
          f32x2 q = __builtin_elementwise_fma(ea, we2[i], xd2[i]) + xs;  // pk_fma + pk_add
          f32x2 ql = __builtin_elementwise_max(q, q * 0.2f);             // pk_mul + 2*max
          p2[j] = __builtin_elementwise_fma(at2[i], ql, p2[j]);          // pk_fma
        }
      }
      float p[EPC];
#pragma unroll
      for (int j = 0; j < EPC; j++) p[j] = p2[j].x + p2[j].y;
#pragma unroll
      for (int o = 16; o > 0; o >>= 1) {           // half-wave butterfly, EPC chains
#pragma unroll
        for (int j = 0; j < EPC; j++) p[j] += __shfl_xor(p[j], o);
      }
      float pe[EPC];
#pragma unroll
      for (int j = 0; j < EPC; j++) {
        pe[j] = __expf(p[j]);
        if (wgt) pe[j] *= wgt[j];
        denom += pe[j];
      }
#pragma unroll
      for (int i = 0; i < PAIRS; i++) {
#pragma unroll
        for (int j = 0; j < EPC; j++) {
          f32x2 pv = {pe[j], pe[j]};
          acc2[i] = __builtin_elementwise_fma(pv, xs2[j][i], acc2[i]);   // pk_fma
        }
      }
    };

    for (int itc = 0; itc < nfullE; ++itc) {       // all slots are edges
      int s[EPC]; float eav[EPC];
#pragma unroll
      for (int k = 0; k < EPC; k++) {
        int2 e = se[start + itc * EPC + k];
        s[k] = e.x; eav[k] = __int_as_float(e.y);
        easum += eav[k];
      }
      body(s, eav, nullptr);
    }
    {                                              // tail: edges + self-loop
      const int base = nfullE * EPC;
      int s[EPC]; float eav[EPC]; float wgt[EPC];
#pragma unroll
      for (int k = 0; k < EPC; k++) {
        int idx = base + k;
        if (idx < deg) {
          int2 e = se[start + idx];
          s[k] = e.x; eav[k] = __int_as_float(e.y);
          easum += eav[k];
        }
      }
      float lan = easum / fmaxf((float)deg, 1.0f);
#pragma unroll
      for (int k = 0; k < EPC; k++) {
        int idx = base + k;
        if (idx >= deg) { s[k] = n; eav[k] = lan; }
        wgt[k] = (idx <= deg) ? 1.f : 0.f;         // idx==deg is the self-loop
      }
      body(s, eav, wgt);
    }

    float inv = 1.f / denom;                       // per-head (per half-wave)
    float vv[VEC], ss = 0.f;
#pragma unroll
    for (int i = 0; i < PAIRS; i++) {
#pragma unroll
      for (int h = 0; h < 2; h++) {
        int k = i * 2 + h;
        float v = fmaf(acc2[i][h], inv, bias[c0 + k]);
        if (DO_SILU) v = v / (1.f + __expf(-v));
        vv[k] = v;
        ss += v * v;
      }
    }
#pragma unroll
    for (int o = 32; o > 0; o >>= 1) ss += __shfl_xor(ss, o);   // full-wave
    float rinv = rsqrtf(ss / (float)D + 1e-5f);

#pragma unroll
    for (int k = 0; k < VEC; k++) {
      float o = vv[k] * rinv * w_ln[c0 + k];
      if (OBF) outb[(size_t)n * D + c0 + k] = f2b(o);
      if (HEAD_GEMM) hrow[w][c0 + k] = o;
    }
    if (HEAD_GEMM) {
      __syncthreads();                             // all 4 waves run all 4 iters
      int t = threadIdx.x;
      if (t < 4 * NCLS) {
        int n4 = t / NCLS, c = t % NCLS;
        const float4* wr = (const float4*)(Wout + c * D2);
        const float4* hr = (const float4*)&hrow[n4][0];
        float sm = 0.f;
#pragma unroll
        for (int q = 0; q < D2 / 4; q++) {
          float4 a = hr[q], b = wr[q];
          sm += a.x * b.x + a.y * b.y + a.z * b.z + a.w * b.w;
        }
        outf[(size_t)(it * NPI + blockIdx.x * 4 + n4) * NCLS + c] = sm;
      }
      __syncthreads();                             // hrow reused next iter
    }
  }
}

// ---------------------------------------------------------------- launch
extern "C" void kernel_launch(void* const* d_in, const int* in_sizes, int n_in,
                              void* d_out, int out_size, void* d_ws, size_t ws_size,
                              hipStream_t stream) {
  const float* x     = (const float*)d_in[0];
  const int*   ei    = (const int*)  d_in[1];
  const float* eattr = (const float*)d_in[2];
  const float* Wl1   = (const float*)d_in[3];
  const float* bl1   = (const float*)d_in[4];
  const float* Wr1   = (const float*)d_in[5];
  const float* br1   = (const float*)d_in[6];
  const float* We1   = (const float*)d_in[7];
  const float* att1  = (const float*)d_in[8];
  const float* bias1 = (const float*)d_in[9];
  const float* Wl2   = (const float*)d_in[10];
  const float* bl2   = (const float*)d_in[11];
  const float* Wr2   = (const float*)d_in[12];
  const float* br2   = (const float*)d_in[13];
  const float* We2   = (const float*)d_in[14];
  const float* att2  = (const float*)d_in[15];
  const float* bias2 = (const float*)d_in[16];
  const float* w_ln1 = (const float*)d_in[17];
  const float* w_ln3 = (const float*)d_in[18];
  const float* W_out = (const float*)d_in[19];
  float* out = (float*)d_out;
  (void)in_sizes; (void)n_in; (void)out_size; (void)ws_size;

  const int* src = ei;
  const int* dst = ei + NE;

  char* wsp = (char*)d_ws;
  auto alloc = [&](size_t nbytes) {
    char* ptr = wsp;
    wsp += ((nbytes + 255) / 256) * 256;
    return ptr;
  };
  int*   cnti   = (int*)  alloc((size_t)NN * 4);   // zeroed via hipMemsetAsync
  int2*  se     = (int2*) alloc((size_t)NN * CAP * 8);   // padded CSR (15.4 MB)
  unsigned short* xb   = (unsigned short*)alloc((size_t)NN * D2 * 2);
  unsigned short* Wc1  = (unsigned short*)alloc((size_t)2 * D1 * D2 * 2);
  unsigned short* Wc2  = (unsigned short*)alloc((size_t)2 * D2 * D1 * 2);
  unsigned short* xl1  = (unsigned short*)alloc((size_t)NN * D1 * 2);  // gather table
  unsigned short* xr1  = (unsigned short*)alloc((size_t)NN * D1 * 2);
  unsigned short* h1b  = (unsigned short*)alloc((size_t)NN * D1 * 2);
  unsigned short* xl2  = (unsigned short*)alloc((size_t)NN * D2 * 2);
  unsigned short* xr2  = (unsigned short*)alloc((size_t)NN * D2 * 2);

  // --- preamble: memset + fused cast/CSR-build (persistent grid) ---
  hipMemsetAsync(cnti, 0, (size_t)NNP * 4, stream);
  k_build<<<BGRID, 256, 0, stream>>>(
      x, Wl1, Wr1, Wl2, Wr2, src, dst, eattr, cnti, se, xb, Wc1, Wc2);

  const int MB = (NN + 127) / 128;   // 235 row-tiles

  // --- layer 1: [xl1|xr1] = x @ [Wl1;Wr1]^T + [bl1;br1]  (split bf16 out) ---
  gemm_mfma<128, 4, 64><<<dim3(2 * D1 / 128, MB), 256, 0, stream>>>(
      xb, Wc1, bl1, br1, D1, xl1, xr1, NN, 2 * D1, D2);
  k_gat_node<D1, 4, true, true, false><<<GB, 256, 0, stream>>>(
      se, cnti, xl1, xr1, We1, att1, bias1, w_ln1, nullptr, h1b, nullptr);

  // --- layer 2: [xl2|xr2] = h1 @ [Wl2;Wr2]^T + [bl2;br2]  (split bf16 out) ---
  gemm_mfma<128, 4, 64><<<dim3(2 * D2 / 128, MB), 256, 0, stream>>>(
      h1b, Wc2, bl2, br2, D2, xl2, xr2, NN, 2 * D2, D1);
  k_gat_node<D2, 8, false, false, true><<<GB, 256, 0, stream>>>(
      se, cnti, xl2, xr2, We2, att2, bias2, w_ln3, W_out, nullptr, out);
}

// Round 12
// 257.563 us; speedup vs baseline: 1.0969x; 1.0969x over previous
//
#include <hip/hip_runtime.h>
#include <cstddef>

#define NN   30000
#define NNP  30016          /* NN ints rounded to 256B alloc granularity */
#define NE   240000
#define D1   512
#define D2   128
#define NCLS 20
#define CAP  64             /* padded-CSR slots per node; Poisson(8) tail @64 ~ 1e-38 */
#define CAST_TOT 1025536          /* x(960000) + 4 weights(16384 ea), float4 units */
#define IDG_TOT  (CAST_TOT + NE)  /* + one thread per edge for CSR-build atomics */

typedef __attribute__((ext_vector_type(8))) short short8;
typedef __attribute__((ext_vector_type(4))) float f32x4;
typedef __attribute__((ext_vector_type(2))) float f32x2;

__device__ __forceinline__ unsigned short f2b(float f) {
  union { float f; unsigned int u; } c; c.f = f;
  unsigned int r = (c.u + 0x7fff + ((c.u >> 16) & 1)) >> 16;  // RNE
  return (unsigned short)r;
}
__device__ __forceinline__ float b2f(unsigned short u) {
  union { unsigned int u; float f; } c; c.u = (unsigned int)u << 16;
  return c.f;
}
// two packed bf16 (little-endian: low half = even channel) -> f32x2
__device__ __forceinline__ f32x2 bpair(unsigned int t) {
  f32x2 r;
  r.x = __uint_as_float(t << 16);
  r.y = __uint_as_float(t & 0xffff0000u);
  return r;
}

// ---------------------------------------------------------------- cast + padded-CSR build
// R9 form (non-persistent; R11 persistence regressed). lsum atomics removed in
// R9 (la computed inside gat). Only the cnti slot-allocating atomic remains.
__global__ __launch_bounds__(256) void k_build(
    const float* __restrict__ x,
    const float* __restrict__ Wl1, const float* __restrict__ Wr1,
    const float* __restrict__ Wl2, const float* __restrict__ Wr2,
    const int* __restrict__ src, const int* __restrict__ dst,
    const float* __restrict__ eattr,
    int* __restrict__ cnti,
    int2* __restrict__ se,
    unsigned short* __restrict__ xb,
    unsigned short* __restrict__ Wc1, unsigned short* __restrict__ Wc2) {
  int i = blockIdx.x * 256 + threadIdx.x;
  if (i >= IDG_TOT) return;
  if (i >= CAST_TOT) {                 // CSR build atomics
    int e = i - CAST_TOT;
    int d = dst[e];
    int pos = atomicAdd(&cnti[d], 1);
    if (pos < CAP) se[(size_t)d * CAP + pos] = make_int2(src[e], __float_as_int(eattr[e]));
    return;
  }
  const float* in; unsigned short* outp; int off;
  if      (i <  960000) { in = x;   outp = xb;          off = i; }
  else if (i <  976384) { in = Wl1; outp = Wc1;         off = i -  960000; }
  else if (i <  992768) { in = Wr1; outp = Wc1 + 65536; off = i -  976384; }
  else if (i < 1009152) { in = Wl2; outp = Wc2;         off = i -  992768; }
  else                  { in = Wr2; outp = Wc2 + 65536; off = i - 1009152; }
  float4 v = ((const float4*)in)[off];
  ushort4 o;
  o.x = f2b(v.x); o.y = f2b(v.y); o.z = f2b(v.z); o.w = f2b(v.w);
  ((ushort4*)outp)[off] = o;
}

// ---------------------------------------------------------------- bf16 MFMA GEMM
// [Cl|Cr][m,n] = sum_k A[m,k]*W[n,k] + bias, W = [Wl;Wr] concat in n; split out.
// m97-style staging: UNPADDED LDS, global_load_lds width=16. BK=64 (R10's
// BK=128 regressed +16.6us — m132 replicated; do not revisit).
// R12: XCD-clustering swizzle. Old 2D grid made the NBN bn-blocks sharing one
// A row-tile CONSECUTIVE linear ids -> round-robin put them on NBN different
// XCDs -> each XCD's L2 fetched its own A-tile copy (gemm1: 8x7.7=61MB fill
// for 7.7MB unique). Now: 1D grid, ids of one bm-tile's bn-blocks are = same
// value mod 8 -> same XCD -> A-tile fetched once per XCD. Dead blocks (bmb >=
// MBT) return uniformly before any barrier.
// R9 epilogue: LDS-staged vectorized C-write (short8, 4 rows x 256B per
// wave-store). Requires BN | Nhalf (128|512, 128|128). No OOB row guard on
// loads (reads past M land in later workspace buffers); store masks rows >= M.
template <int BN, int NT, int BK, int NBN>   // NBN = grid tiles along n
__global__ __launch_bounds__(256) void gemm_mfma(
    const unsigned short* __restrict__ A, const unsigned short* __restrict__ W,
    const float* __restrict__ bl, const float* __restrict__ br, int Nhalf,
    unsigned short* __restrict__ Cl, unsigned short* __restrict__ Cr,
    int M, int N, int K) {
  constexpr int BM = 128, LDK = BK;    // unpadded (global_load_lds)
  constexpr int RPI = 512 / BK;        // rows per wave per load issue (8@64)
  constexpr int LPR = BK / 8;          // lanes per row (8@64)
  constexpr int CPAD = BN + 8;         // C-stage stride (16B-aligned rows)
  constexpr int SM_STAGE = BM * LDK + BN * LDK;
  constexpr int SM_C = BM * CPAD;
  constexpr int SMEM = SM_STAGE > SM_C ? SM_STAGE : SM_C;
  const int MBT = (M + BM - 1) / BM;   // 235 row-tiles
  // --- XCD-clustering decode: id = r + 8*bnb + 8*NBN*g ; bmb = g*8 + r ---
  {
  }
  const int id = blockIdx.x;
  const int g = id / (8 * NBN);
  const int rem = id % (8 * NBN);
  const int r8 = rem & 7;
  const int bnb = rem >> 3;
  const int bmb = g * 8 + r8;
  if (bmb >= MBT) return;              // uniform dead-block exit (no barriers yet)
  __shared__ __align__(16) unsigned short smem[SMEM];
  unsigned short* As = smem;
  unsigned short* Bs = smem + BM * LDK;
  const int bm = bmb * BM;
  const int bn = bnb * BN;
  const int tid = threadIdx.x;
  const int lane = tid & 63;
  const int wid = __builtin_amdgcn_readfirstlane(tid >> 6);  // wave-uniform (SGPR)
  const int wm = (wid >> 1) * 64;
  const int wn = (wid & 1) * (NT * 16);
  const int l16 = lane & 15, lq = lane >> 4;
  const int lrow = lane / LPR;         // staging: row within RPI
  const int lcol = (lane % LPR) * 8;   // staging: k-offset (8 bf16 = 16 B)

  f32x4 acc[4][NT];
#pragma unroll
  for (int i = 0; i < 4; ++i)
#pragma unroll
    for (int j = 0; j < NT; ++j) acc[i][j] = (f32x4){0.f, 0.f, 0.f, 0.f};

  for (int k0 = 0; k0 < K; k0 += BK) {
#pragma unroll
    for (int p = 0; p < BM / (4 * RPI); ++p) {
      int r = p * (4 * RPI) + wid * RPI;
      const unsigned short* gp = A + (size_t)(bm + r + lrow) * K + k0 + lcol;
      __builtin_amdgcn_global_load_lds(
          (const __attribute__((address_space(1))) unsigned int*)gp,
          (__attribute__((address_space(3))) unsigned int*)(As + (size_t)r * LDK),
          16, 0, 0);
    }
#pragma unroll
    for (int p = 0; p < BN / (4 * RPI); ++p) {
      int r = p * (4 * RPI) + wid * RPI;
      const unsigned short* gp = W + (size_t)(bn + r + lrow) * K + k0 + lcol;
      __builtin_amdgcn_global_load_lds(
          (const __attribute__((address_space(1))) unsigned int*)gp,
          (__attribute__((address_space(3))) unsigned int*)(Bs + (size_t)r * LDK),
          16, 0, 0);
    }
    __syncthreads();
#pragma unroll
    for (int kh = 0; kh < BK / 32; ++kh) {
      short8 af[4], bfr[NT];
#pragma unroll
      for (int mt = 0; mt < 4; ++mt)
        af[mt] = *(const short8*)&As[(wm + mt * 16 + l16) * LDK + kh * 32 + lq * 8];
#pragma unroll
      for (int nt = 0; nt < NT; ++nt)
        bfr[nt] = *(const short8*)&Bs[(wn + nt * 16 + l16) * LDK + kh * 32 + lq * 8];
#pragma unroll
      for (int mt = 0; mt < 4; ++mt)
#pragma unroll
        for (int nt = 0; nt < NT; ++nt)
          acc[mt][nt] = __builtin_amdgcn_mfma_f32_16x16x32_bf16(
              af[mt], bfr[nt], acc[mt][nt], 0, 0, 0);
    }
    __syncthreads();
  }
  // K-loop ended with a barrier: safe to reuse smem as the C-stage.
  unsigned short* Cs = smem;           // [BM][CPAD]
  const bool left = bn < Nhalf;        // block-uniform (BN | Nhalf)
  const int ccb = left ? bn : bn - Nhalf;
  const float* bptr = left ? bl : br;
  unsigned short* Cp = left ? Cl : Cr;

#pragma unroll
  for (int nt = 0; nt < NT; ++nt) {
    int lc = wn + nt * 16 + l16;
    float b = bptr[ccb + lc];
#pragma unroll
    for (int mt = 0; mt < 4; ++mt)
#pragma unroll
      for (int r = 0; r < 4; ++r)
        Cs[(wm + mt * 16 + lq * 4 + r) * CPAD + lc] = f2b(acc[mt][nt][r] + b);
  }
  __syncthreads();
  constexpr int CHR = BN / 8;                  // 16B chunks per row
  constexpr int NPASS = BM * CHR / 256;        // chunks per thread
#pragma unroll
  for (int p = 0; p < NPASS; ++p) {
    int c = p * 256 + tid;
    int row = c / CHR, col8 = (c % CHR) * 8;
    if (bm + row < M)
      *(short8*)&Cp[(size_t)(bm + row) * Nhalf + ccb + col8] =
          *(const short8*)&Cs[row * CPAD + col8];
  }
}

// ---------------------------------------------------------------- fused GATv2 aggregate
// R9 form exactly (anchor 258.4us). ONE wave per destination node, 4 nodes per
// 256-thread block, per-chunk se broadcast load. Packed f32x2 VOP3P math.
// EPC=4 (gat1) / 8 (gat2). In-kernel la (easum over full chunks; tail does
// edges-remainder + self-loop under wgt mask).
// Cross-round invariant: per-node wave lifetime ~5.4us regardless of structure
// (R1 ping-pong, R6 16-wave blocks, R7 readlane, R11 persistence all neutral-
// to-negative) — gat is at its random-gather memory-path equilibrium; only
// traffic/work removal pays. Keep VGPR <= 64.
template <int D, int EPC, bool DO_SILU, bool OBF, bool HEAD_GEMM>
__global__ __launch_bounds__(256) void k_gat_node(
    const int2* __restrict__ se,
    const int* __restrict__ cnti,
    const unsigned short* __restrict__ xl, const unsigned short* __restrict__ xr,
    const float* __restrict__ We, const float* __restrict__ att,
    const float* __restrict__ bias, const float* __restrict__ w_ln,
    const float* __restrict__ Wout,
    unsigned short* __restrict__ outb, float* __restrict__ outf) {
  constexpr int VEC = D / 64;      // channels per lane (8 for D1, 2 for D2)
  constexpr int PAIRS = VEC / 2;   // f32x2 pairs per lane
  const int w = __builtin_amdgcn_readfirstlane(threadIdx.x) >> 6;  // SGPR wave id
  const int n = blockIdx.x * 4 + w;                                // SGPR node
  const int lane = threadIdx.x & 63;
  const int c0 = lane * VEC;

  f32x2 xd2[PAIRS], we2[PAIRS], at2[PAIRS], acc2[PAIRS];
  {
    unsigned int tr[PAIRS];
    if constexpr (PAIRS == 4) {
      uint4 t = *(const uint4*)(xr + (size_t)n * D + c0);
      tr[0] = t.x; tr[1] = t.y; tr[2] = t.z; tr[3] = t.w;
    } else {
      tr[0] = *(const unsigned int*)(xr + (size_t)n * D + c0);
    }
    const f32x2* Wep = (const f32x2*)(We + c0);
    const f32x2* atp = (const f32x2*)(att + c0);
#pragma unroll
    for (int i = 0; i < PAIRS; i++) {
      xd2[i] = bpair(tr[i]);
      we2[i] = Wep[i];
      at2[i] = atp[i];
      acc2[i] = (f32x2){0.f, 0.f};
    }
  }

  const int start = n * CAP;
  const int deg = cnti[n];
  float denom = 0.f;
  float easum = 0.f;
  const int nfullE = deg / EPC;                 // full chunks of EDGES only

  // shared chunk body; wgt==nullptr folds the mask away at the full-chunk site
  auto body = [&](const int (&s)[EPC], const float (&eav)[EPC], const float* wgt) {
    unsigned int uu[EPC][PAIRS];
#pragma unroll
    for (int k = 0; k < EPC; k++) {                // EPC gathers in flight
      if constexpr (PAIRS == 4) {
        uint4 t = *(const uint4*)(xl + (size_t)s[k] * D + c0);
        uu[k][0] = t.x; uu[k][1] = t.y; uu[k][2] = t.z; uu[k][3] = t.w;
      } else {
        uu[k][0] = *(const unsigned int*)(xl + (size_t)s[k] * D + c0);
      }
    }
    f32x2 xs2[EPC][PAIRS];
    f32x2 p2[EPC];
#pragma unroll
    for (int j = 0; j < EPC; j++) p2[j] = (f32x2){0.f, 0.f};
#pragma unroll
    for (int i = 0; i < PAIRS; i++) {
#pragma unroll
      for (int j = 0; j < EPC; j++) {
        f32x2 xs = bpair(uu[j][i]);
        xs2[j][i] = xs;
        f32x2 ea = {eav[j], eav[j]};
        f32x2 q = __builtin_elementwise_fma(ea, we2[i], xd2[i]) + xs;  // pk_fma + pk_add
        f32x2 ql = __builtin_elementwise_max(q, q * 0.2f);             // pk_mul + 2*max
        p2[j] = __builtin_elementwise_fma(at2[i], ql, p2[j]);          // pk_fma
      }
    }
    float p[EPC];
#pragma unroll
    for (int j = 0; j < EPC; j++) p[j] = p2[j].x + p2[j].y;
#pragma unroll
    for (int o = 16; o > 0; o >>= 1) {           // half-wave butterfly, EPC chains
#pragma unroll
      for (int j = 0; j < EPC; j++) p[j] += __shfl_xor(p[j], o);
    }
    float pe[EPC];
#pragma unroll
    for (int j = 0; j < EPC; j++) {
      pe[j] = __expf(p[j]);
      if (wgt) pe[j] *= wgt[j];
      denom += pe[j];
    }
#pragma unroll
    for (int i = 0; i < PAIRS; i++) {
#pragma unroll
      for (int j = 0; j < EPC; j++) {
        f32x2 pv = {pe[j], pe[j]};
        acc2[i] = __builtin_elementwise_fma(pv, xs2[j][i], acc2[i]);   // pk_fma
      }
    }
  };

  for (int it = 0; it < nfullE; ++it) {          // all slots are edges
    int s[EPC]; float eav[EPC];
#pragma unroll
    for (int k = 0; k < EPC; k++) {
      int2 e = se[start + it * EPC + k];
      s[k] = e.x; eav[k] = __int_as_float(e.y);
      easum += eav[k];
    }
    body(s, eav, nullptr);
  }
  {                                              // tail: edges + self-loop
    const int base = nfullE * EPC;
    int s[EPC]; float eav[EPC]; float wgt[EPC];
#pragma unroll
    for (int k = 0; k < EPC; k++) {
      int idx = base + k;
      if (idx < deg) {
        int2 e = se[start + idx];
        s[k] = e.x; eav[k] = __int_as_float(e.y);
        easum += eav[k];
      }
    }
    float lan = easum / fmaxf((float)deg, 1.0f);
#pragma unroll
    for (int k = 0; k < EPC; k++) {
      int idx = base + k;
      if (idx >= deg) { s[k] = n; eav[k] = lan; }
      wgt[k] = (idx <= deg) ? 1.f : 0.f;         // idx==deg is the self-loop
    }
    body(s, eav, wgt);
  }

  float inv = 1.f / denom;                       // per-head (per half-wave)
  float vv[VEC], ss = 0.f;
#pragma unroll
  for (int i = 0; i < PAIRS; i++) {
#pragma unroll
    for (int h = 0; h < 2; h++) {
      int k = i * 2 + h;
      float v = fmaf(acc2[i][h], inv, bias[c0 + k]);
      if (DO_SILU) v = v / (1.f + __expf(-v));
      vv[k] = v;
      ss += v * v;
    }
  }
#pragma unroll
  for (int o = 32; o > 0; o >>= 1) ss += __shfl_xor(ss, o);   // full-wave
  float rinv = rsqrtf(ss / (float)D + 1e-5f);

  __shared__ __align__(16) float hrow[4][D2];
#pragma unroll
  for (int k = 0; k < VEC; k++) {
    float o = vv[k] * rinv * w_ln[c0 + k];
    if (OBF) outb[(size_t)n * D + c0 + k] = f2b(o);
    if (HEAD_GEMM) hrow[w][c0 + k] = o;
  }
  if (HEAD_GEMM) {
    __syncthreads();                             // no early returns: NN % 4 == 0
    int t = threadIdx.x;
    if (t < 4 * NCLS) {
      int n4 = t / NCLS, c = t % NCLS;
      const float4* wr = (const float4*)(Wout + c * D2);
      const float4* hr = (const float4*)&hrow[n4][0];
      float sm = 0.f;
#pragma unroll
      for (int q = 0; q < D2 / 4; q++) {
        float4 a = hr[q], b = wr[q];
        sm += a.x * b.x + a.y * b.y + a.z * b.z + a.w * b.w;
      }
      outf[(size_t)(blockIdx.x * 4 + n4) * NCLS + c] = sm;
    }
  }
}

// ---------------------------------------------------------------- launch
extern "C" void kernel_launch(void* const* d_in, const int* in_sizes, int n_in,
                              void* d_out, int out_size, void* d_ws, size_t ws_size,
                              hipStream_t stream) {
  const float* x     = (const float*)d_in[0];
  const int*   ei    = (const int*)  d_in[1];
  const float* eattr = (const float*)d_in[2];
  const float* Wl1   = (const float*)d_in[3];
  const float* bl1   = (const float*)d_in[4];
  const float* Wr1   = (const float*)d_in[5];
  const float* br1   = (const float*)d_in[6];
  const float* We1   = (const float*)d_in[7];
  const float* att1  = (const float*)d_in[8];
  const float* bias1 = (const float*)d_in[9];
  const float* Wl2   = (const float*)d_in[10];
  const float* bl2   = (const float*)d_in[11];
  const float* Wr2   = (const float*)d_in[12];
  const float* br2   = (const float*)d_in[13];
  const float* We2   = (const float*)d_in[14];
  const float* att2  = (const float*)d_in[15];
  const float* bias2 = (const float*)d_in[16];
  const float* w_ln1 = (const float*)d_in[17];
  const float* w_ln3 = (const float*)d_in[18];
  const float* W_out = (const float*)d_in[19];
  float* out = (float*)d_out;
  (void)in_sizes; (void)n_in; (void)out_size; (void)ws_size;

  const int* src = ei;
  const int* dst = ei + NE;

  char* wsp = (char*)d_ws;
  auto alloc = [&](size_t nbytes) {
    char* ptr = wsp;
    wsp += ((nbytes + 255) / 256) * 256;
    return ptr;
  };
  int*   cnti   = (int*)  alloc((size_t)NN * 4);   // zeroed via hipMemsetAsync
  int2*  se     = (int2*) alloc((size_t)NN * CAP * 8);   // padded CSR (15.4 MB)
  unsigned short* xb   = (unsigned short*)alloc((size_t)NN * D2 * 2);
  unsigned short* Wc1  = (unsigned short*)alloc((size_t)2 * D1 * D2 * 2);
  unsigned short* Wc2  = (unsigned short*)alloc((size_t)2 * D2 * D1 * 2);
  unsigned short* xl1  = (unsigned short*)alloc((size_t)NN * D1 * 2);  // gather table
  unsigned short* xr1  = (unsigned short*)alloc((size_t)NN * D1 * 2);
  unsigned short* h1b  = (unsigned short*)alloc((size_t)NN * D1 * 2);
  unsigned short* xl2  = (unsigned short*)alloc((size_t)NN * D2 * 2);
  unsigned short* xr2  = (unsigned short*)alloc((size_t)NN * D2 * 2);

  // --- preamble: memset + fused cast/CSR-build ---
  hipMemsetAsync(cnti, 0, (size_t)NNP * 4, stream);
  k_build<<<(IDG_TOT + 255) / 256, 256, 0, stream>>>(
      x, Wl1, Wr1, Wl2, Wr2, src, dst, eattr, cnti, se, xb, Wc1, Wc2);

  const int GB = NN / 4;             // 4 nodes/block, 1 wave each (NN % 4 == 0)
  // XCD-clustered 1D grids: 30 row-groups x 8 xcd-slots x NBN col-tiles
  const int G1 = 30 * 8 * 8;         // gemm1: NBN=8 -> 1920 (40 dead)
  const int G2 = 30 * 8 * 2;         // gemm2: NBN=2 -> 480  (10 dead)

  // --- layer 1: [xl1|xr1] = x @ [Wl1;Wr1]^T + [bl1;br1]  (split bf16 out) ---
  gemm_mfma<128, 4, 64, 8><<<G1, 256, 0, stream>>>(
      xb, Wc1, bl1, br1, D1, xl1, xr1, NN, 2 * D1, D2);
  k_gat_node<D1, 4, true, true, false><<<GB, 256, 0, stream>>>(
      se, cnti, xl1, xr1, We1, att1, bias1, w_ln1, nullptr, h1b, nullptr);

  // --- layer 2: [xl2|xr2] = h1 @ [Wl2;Wr2]^T + [bl2;br2]  (split bf16 out) ---
  gemm_mfma<128, 4, 64, 2><<<G2, 256, 0, stream>>>(
      h1b, Wc2, bl2, br2, D2, xl2, xr2, NN, 2 * D2, D1);
  k_gat_node<D2, 8, false, false, true><<<GB, 256, 0, stream>>>(
      se, cnti, xl2, xr2, We2, att2, bias2, w_ln3, W_out, nullptr, out);
}

// Round 13
// 249.752 us; speedup vs baseline: 1.1312x; 1.0313x over previous
//
#include <hip/hip_runtime.h>
#include <cstddef>

#define NN   30000
#define NNP  30016          /* NN ints rounded to 256B alloc granularity */
#define NE   240000
#define D1   512
#define D2   128
#define NCLS 20
#define CAP  64             /* padded-CSR slots per node; Poisson(8) tail @64 ~ 1e-38 */
#define CAST_TOT 1025536          /* x(960000) + 4 weights(16384 ea), float4 units */
#define ZERO_TOT (NNP / 4)        /* int4 zero-stores for cnti (7504) */
#define KC_TOT  (CAST_TOT + ZERO_TOT)
#define CSRB    ((NE + 255) / 256)    /* 938 CSR blocks folded into gemm1 */

typedef __attribute__((ext_vector_type(8))) short short8;
typedef __attribute__((ext_vector_type(4))) float f32x4;
typedef __attribute__((ext_vector_type(2))) float f32x2;

__device__ __forceinline__ unsigned short f2b(float f) {
  union { float f; unsigned int u; } c; c.f = f;
  unsigned int r = (c.u + 0x7fff + ((c.u >> 16) & 1)) >> 16;  // RNE
  return (unsigned short)r;
}
__device__ __forceinline__ float b2f(unsigned short u) {
  union { unsigned int u; float f; } c; c.u = (unsigned int)u << 16;
  return c.f;
}
// two packed bf16 (little-endian: low half = even channel) -> f32x2
__device__ __forceinline__ f32x2 bpair(unsigned int t) {
  f32x2 r;
  r.x = __uint_as_float(t << 16);
  r.y = __uint_as_float(t & 0xffff0000u);
  return r;
}

// ---------------------------------------------------------------- cast + cnti zero
// R13: casts + cnti zeroing in one kernel (memset dispatch removed). The CSR
// edge scatter moved into gemm1's grid (fat kernel) — it only feeds gat1, so
// it can overlap gemm1 which needs only xb/Wc1.
__global__ __launch_bounds__(256) void k_cast(
    const float* __restrict__ x,
    const float* __restrict__ Wl1, const float* __restrict__ Wr1,
    const float* __restrict__ Wl2, const float* __restrict__ Wr2,
    int* __restrict__ cnti,
    unsigned short* __restrict__ xb,
    unsigned short* __restrict__ Wc1, unsigned short* __restrict__ Wc2) {
  int i = blockIdx.x * 256 + threadIdx.x;
  if (i >= KC_TOT) return;
  if (i >= CAST_TOT) {                 // zero cnti (NNP ints = ZERO_TOT int4s)
    ((int4*)cnti)[i - CAST_TOT] = make_int4(0, 0, 0, 0);
    return;
  }
  const float* in; unsigned short* outp; int off;
  if      (i <  960000) { in = x;   outp = xb;          off = i; }
  else if (i <  976384) { in = Wl1; outp = Wc1;         off = i -  960000; }
  else if (i <  992768) { in = Wr1; outp = Wc1 + 65536; off = i -  976384; }
  else if (i < 1009152) { in = Wl2; outp = Wc2;         off = i -  992768; }
  else                  { in = Wr2; outp = Wc2 + 65536; off = i - 1009152; }
  float4 v = ((const float4*)in)[off];
  ushort4 o;
  o.x = f2b(v.x); o.y = f2b(v.y); o.z = f2b(v.z); o.w = f2b(v.w);
  ((ushort4*)outp)[off] = o;
}

// ---------------------------------------------------------------- bf16 MFMA GEMM (+ optional fused CSR blocks)
// [Cl|Cr][m,n] = sum_k A[m,k]*W[n,k] + bias, W = [Wl;Wr] concat in n; split out.
// m97-style staging: UNPADDED LDS, global_load_lds width=16. BK=64 (R10's
// BK=128 regressed +16.6us — m132 replicated; do not revisit).
// R13 fat kernel: blocks [0, nCsrB) run the padded-CSR edge scatter (one
// 256-edge chunk each, uniform return before any barrier) and overlap the
// gemm blocks behind them — CSR output (se/cnti) is consumed only by gat1,
// which runs after this kernel. Edge-insertion order changes vs a standalone
// build; within-node order was already atomic-nondeterministic (absmax
// invariant across all prior reorderings).
// R12 XCD-clustering swizzle (neutral but free): the NBN bn-blocks sharing an
// A row-tile get ids = same value mod 8 -> same XCD L2.
// R9 epilogue: LDS-staged vectorized C-write (short8, 4 rows x 256B per
// wave-store). Requires BN | Nhalf (128|512, 128|128). No OOB row guard on
// loads (reads past M land in later workspace buffers); store masks rows >= M.
template <int BN, int NT, int BK, int NBN>   // NBN = grid tiles along n
__global__ __launch_bounds__(256) void gemm_mfma(
    const unsigned short* __restrict__ A, const unsigned short* __restrict__ W,
    const float* __restrict__ bl, const float* __restrict__ br, int Nhalf,
    unsigned short* __restrict__ Cl, unsigned short* __restrict__ Cr,
    int M, int N, int K,
    int nCsrB, const int* __restrict__ esrc, const int* __restrict__ edst,
    const float* __restrict__ eattr, int* __restrict__ cnti,
    int2* __restrict__ sed) {
  constexpr int BM = 128, LDK = BK;    // unpadded (global_load_lds)
  constexpr int RPI = 512 / BK;        // rows per wave per load issue (8@64)
  constexpr int LPR = BK / 8;          // lanes per row (8@64)
  constexpr int CPAD = BN + 8;         // C-stage stride (16B-aligned rows)
  constexpr int SM_STAGE = BM * LDK + BN * LDK;
  constexpr int SM_C = BM * CPAD;
  constexpr int SMEM = SM_STAGE > SM_C ? SM_STAGE : SM_C;
  const int MBT = (M + BM - 1) / BM;   // 235 row-tiles
  const int id = blockIdx.x;
  if (id < nCsrB) {                    // fused CSR scatter (runs first, overlaps)
    int e = id * 256 + threadIdx.x;
    if (e < NE) {
      int d = edst[e];
      int pos = atomicAdd(&cnti[d], 1);
      if (pos < CAP)
        sed[(size_t)d * CAP + pos] = make_int2(esrc[e], __float_as_int(eattr[e]));
    }
    return;
  }
  // --- XCD-clustering decode: gid = r + 8*bnb + 8*NBN*g ; bmb = g*8 + r ---
  const int gid = id - nCsrB;
  const int g = gid / (8 * NBN);
  const int rem = gid % (8 * NBN);
  const int r8 = rem & 7;
  const int bnb = rem >> 3;
  const int bmb = g * 8 + r8;
  if (bmb >= MBT) return;              // uniform dead-block exit (no barriers yet)
  __shared__ __align__(16) unsigned short smem[SMEM];
  unsigned short* As = smem;
  unsigned short* Bs = smem + BM * LDK;
  const int bm = bmb * BM;
  const int bn = bnb * BN;
  const int tid = threadIdx.x;
  const int lane = tid & 63;
  const int wid = __builtin_amdgcn_readfirstlane(tid >> 6);  // wave-uniform (SGPR)
  const int wm = (wid >> 1) * 64;
  const int wn = (wid & 1) * (NT * 16);
  const int l16 = lane & 15, lq = lane >> 4;
  const int lrow = lane / LPR;         // staging: row within RPI
  const int lcol = (lane % LPR) * 8;   // staging: k-offset (8 bf16 = 16 B)

  f32x4 acc[4][NT];
#pragma unroll
  for (int i = 0; i < 4; ++i)
#pragma unroll
    for (int j = 0; j < NT; ++j) acc[i][j] = (f32x4){0.f, 0.f, 0.f, 0.f};

  for (int k0 = 0; k0 < K; k0 += BK) {
#pragma unroll
    for (int p = 0; p < BM / (4 * RPI); ++p) {
      int r = p * (4 * RPI) + wid * RPI;
      const unsigned short* gp = A + (size_t)(bm + r + lrow) * K + k0 + lcol;
      __builtin_amdgcn_global_load_lds(
          (const __attribute__((address_space(1))) unsigned int*)gp,
          (__attribute__((address_space(3))) unsigned int*)(As + (size_t)r * LDK),
          16, 0, 0);
    }
#pragma unroll
    for (int p = 0; p < BN / (4 * RPI); ++p) {
      int r = p * (4 * RPI) + wid * RPI;
      const unsigned short* gp = W + (size_t)(bn + r + lrow) * K + k0 + lcol;
      __builtin_amdgcn_global_load_lds(
          (const __attribute__((address_space(1))) unsigned int*)gp,
          (__attribute__((address_space(3))) unsigned int*)(Bs + (size_t)r * LDK),
          16, 0, 0);
    }
    __syncthreads();
#pragma unroll
    for (int kh = 0; kh < BK / 32; ++kh) {
      short8 af[4], bfr[NT];
#pragma unroll
      for (int mt = 0; mt < 4; ++mt)
        af[mt] = *(const short8*)&As[(wm + mt * 16 + l16) * LDK + kh * 32 + lq * 8];
#pragma unroll
      for (int nt = 0; nt < NT; ++nt)
        bfr[nt] = *(const short8*)&Bs[(wn + nt * 16 + l16) * LDK + kh * 32 + lq * 8];
#pragma unroll
      for (int mt = 0; mt < 4; ++mt)
#pragma unroll
        for (int nt = 0; nt < NT; ++nt)
          acc[mt][nt] = __builtin_amdgcn_mfma_f32_16x16x32_bf16(
              af[mt], bfr[nt], acc[mt][nt], 0, 0, 0);
    }
    __syncthreads();
  }
  // K-loop ended with a barrier: safe to reuse smem as the C-stage.
  unsigned short* Cs = smem;           // [BM][CPAD]
  const bool left = bn < Nhalf;        // block-uniform (BN | Nhalf)
  const int ccb = left ? bn : bn - Nhalf;
  const float* bptr = left ? bl : br;
  unsigned short* Cp = left ? Cl : Cr;

#pragma unroll
  for (int nt = 0; nt < NT; ++nt) {
    int lc = wn + nt * 16 + l16;
    float b = bptr[ccb + lc];
#pragma unroll
    for (int mt = 0; mt < 4; ++mt)
#pragma unroll
      for (int r = 0; r < 4; ++r)
        Cs[(wm + mt * 16 + lq * 4 + r) * CPAD + lc] = f2b(acc[mt][nt][r] + b);
  }
  __syncthreads();
  constexpr int CHR = BN / 8;                  // 16B chunks per row
  constexpr int NPASS = BM * CHR / 256;        // chunks per thread
#pragma unroll
  for (int p = 0; p < NPASS; ++p) {
    int c = p * 256 + tid;
    int row = c / CHR, col8 = (c % CHR) * 8;
    if (bm + row < M)
      *(short8*)&Cp[(size_t)(bm + row) * Nhalf + ccb + col8] =
          *(const short8*)&Cs[row * CPAD + col8];
  }
}

// ---------------------------------------------------------------- fused GATv2 aggregate
// R9 form exactly (anchor). ONE wave per destination node, 4 nodes per
// 256-thread block, per-chunk se broadcast load. Packed f32x2 VOP3P math.
// EPC=4 (gat1) / 8 (gat2). In-kernel la (easum over full chunks; tail does
// edges-remainder + self-loop under wgt mask).
// Cross-round invariant: per-node wave lifetime ~5.4us regardless of structure
// (R1 ping-pong, R6 16-wave blocks, R7 readlane, R11 persistence all neutral-
// to-negative) — gat is at its random-gather memory-path equilibrium; only
// traffic/work removal pays. Keep VGPR <= 64.
template <int D, int EPC, bool DO_SILU, bool OBF, bool HEAD_GEMM>
__global__ __launch_bounds__(256) void k_gat_node(
    const int2* __restrict__ se,
    const int* __restrict__ cnti,
    const unsigned short* __restrict__ xl, const unsigned short* __restrict__ xr,
    const float* __restrict__ We, const float* __restrict__ att,
    const float* __restrict__ bias, const float* __restrict__ w_ln,
    const float* __restrict__ Wout,
    unsigned short* __restrict__ outb, float* __restrict__ outf) {
  constexpr int VEC = D / 64;      // channels per lane (8 for D1, 2 for D2)
  constexpr int PAIRS = VEC / 2;   // f32x2 pairs per lane
  const int w = __builtin_amdgcn_readfirstlane(threadIdx.x) >> 6;  // SGPR wave id
  const int n = blockIdx.x * 4 + w;                                // SGPR node
  const int lane = threadIdx.x & 63;
  const int c0 = lane * VEC;

  f32x2 xd2[PAIRS], we2[PAIRS], at2[PAIRS], acc2[PAIRS];
  {
    unsigned int tr[PAIRS];
    if constexpr (PAIRS == 4) {
      uint4 t = *(const uint4*)(xr + (size_t)n * D + c0);
      tr[0] = t.x; tr[1] = t.y; tr[2] = t.z; tr[3] = t.w;
    } else {
      tr[0] = *(const unsigned int*)(xr + (size_t)n * D + c0);
    }
    const f32x2* Wep = (const f32x2*)(We + c0);
    const f32x2* atp = (const f32x2*)(att + c0);
#pragma unroll
    for (int i = 0; i < PAIRS; i++) {
      xd2[i] = bpair(tr[i]);
      we2[i] = Wep[i];
      at2[i] = atp[i];
      acc2[i] = (f32x2){0.f, 0.f};
    }
  }

  const int start = n * CAP;
  const int deg = cnti[n];
  float denom = 0.f;
  float easum = 0.f;
  const int nfullE = deg / EPC;                 // full chunks of EDGES only

  // shared chunk body; wgt==nullptr folds the mask away at the full-chunk site
  auto body = [&](const int (&s)[EPC], const float (&eav)[EPC], const float* wgt) {
    unsigned int uu[EPC][PAIRS];
#pragma unroll
    for (int k = 0; k < EPC; k++) {                // EPC gathers in flight
      if constexpr (PAIRS == 4) {
        uint4 t = *(const uint4*)(xl + (size_t)s[k] * D + c0);
        uu[k][0] = t.x; uu[k][1] = t.y; uu[k][2] = t.z; uu[k][3] = t.w;
      } else {
        uu[k][0] = *(const unsigned int*)(xl + (size_t)s[k] * D + c0);
      }
    }
    f32x2 xs2[EPC][PAIRS];
    f32x2 p2[EPC];
#pragma unroll
    for (int j = 0; j < EPC; j++) p2[j] = (f32x2){0.f, 0.f};
#pragma unroll
    for (int i = 0; i < PAIRS; i++) {
#pragma unroll
      for (int j = 0; j < EPC; j++) {
        f32x2 xs = bpair(uu[j][i]);
        xs2[j][i] = xs;
        f32x2 ea = {eav[j], eav[j]};
        f32x2 q = __builtin_elementwise_fma(ea, we2[i], xd2[i]) + xs;  // pk_fma + pk_add
        f32x2 ql = __builtin_elementwise_max(q, q * 0.2f);             // pk_mul + 2*max
        p2[j] = __builtin_elementwise_fma(at2[i], ql, p2[j]);          // pk_fma
      }
    }
    float p[EPC];
#pragma unroll
    for (int j = 0; j < EPC; j++) p[j] = p2[j].x + p2[j].y;
#pragma unroll
    for (int o = 16; o > 0; o >>= 1) {           // half-wave butterfly, EPC chains
#pragma unroll
      for (int j = 0; j < EPC; j++) p[j] += __shfl_xor(p[j], o);
    }
    float pe[EPC];
#pragma unroll
    for (int j = 0; j < EPC; j++) {
      pe[j] = __expf(p[j]);
      if (wgt) pe[j] *= wgt[j];
      denom += pe[j];
    }
#pragma unroll
    for (int i = 0; i < PAIRS; i++) {
#pragma unroll
      for (int j = 0; j < EPC; j++) {
        f32x2 pv = {pe[j], pe[j]};
        acc2[i] = __builtin_elementwise_fma(pv, xs2[j][i], acc2[i]);   // pk_fma
      }
    }
  };

  for (int it = 0; it < nfullE; ++it) {          // all slots are edges
    int s[EPC]; float eav[EPC];
#pragma unroll
    for (int k = 0; k < EPC; k++) {
      int2 e = se[start + it * EPC + k];
      s[k] = e.x; eav[k] = __int_as_float(e.y);
      easum += eav[k];
    }
    body(s, eav, nullptr);
  }
  {                                              // tail: edges + self-loop
    const int base = nfullE * EPC;
    int s[EPC]; float eav[EPC]; float wgt[EPC];
#pragma unroll
    for (int k = 0; k < EPC; k++) {
      int idx = base + k;
      if (idx < deg) {
        int2 e = se[start + idx];
        s[k] = e.x; eav[k] = __int_as_float(e.y);
        easum += eav[k];
      }
    }
    float lan = easum / fmaxf((float)deg, 1.0f);
#pragma unroll
    for (int k = 0; k < EPC; k++) {
      int idx = base + k;
      if (idx >= deg) { s[k] = n; eav[k] = lan; }
      wgt[k] = (idx <= deg) ? 1.f : 0.f;         // idx==deg is the self-loop
    }
    body(s, eav, wgt);
  }

  float inv = 1.f / denom;                       // per-head (per half-wave)
  float vv[VEC], ss = 0.f;
#pragma unroll
  for (int i = 0; i < PAIRS; i++) {
#pragma unroll
    for (int h = 0; h < 2; h++) {
      int k = i * 2 + h;
      float v = fmaf(acc2[i][h], inv, bias[c0 + k]);
      if (DO_SILU) v = v / (1.f + __expf(-v));
      vv[k] = v;
      ss += v * v;
    }
  }
#pragma unroll
  for (int o = 32; o > 0; o >>= 1) ss += __shfl_xor(ss, o);   // full-wave
  float rinv = rsqrtf(ss / (float)D + 1e-5f);

  __shared__ __align__(16) float hrow[4][D2];
#pragma unroll
  for (int k = 0; k < VEC; k++) {
    float o = vv[k] * rinv * w_ln[c0 + k];
    if (OBF) outb[(size_t)n * D + c0 + k] = f2b(o);
    if (HEAD_GEMM) hrow[w][c0 + k] = o;
  }
  if (HEAD_GEMM) {
    __syncthreads();                             // no early returns: NN % 4 == 0
    int t = threadIdx.x;
    if (t < 4 * NCLS) {
      int n4 = t / NCLS, c = t % NCLS;
      const float4* wr = (const float4*)(Wout + c * D2);
      const float4* hr = (const float4*)&hrow[n4][0];
      float sm = 0.f;
#pragma unroll
      for (int q = 0; q < D2 / 4; q++) {
        float4 a = hr[q], b = wr[q];
        sm += a.x * b.x + a.y * b.y + a.z * b.z + a.w * b.w;
      }
      outf[(size_t)(blockIdx.x * 4 + n4) * NCLS + c] = sm;
    }
  }
}

// ---------------------------------------------------------------- launch
extern "C" void kernel_launch(void* const* d_in, const int* in_sizes, int n_in,
                              void* d_out, int out_size, void* d_ws, size_t ws_size,
                              hipStream_t stream) {
  const float* x     = (const float*)d_in[0];
  const int*   ei    = (const int*)  d_in[1];
  const float* eattr = (const float*)d_in[2];
  const float* Wl1   = (const float*)d_in[3];
  const float* bl1   = (const float*)d_in[4];
  const float* Wr1   = (const float*)d_in[5];
  const float* br1   = (const float*)d_in[6];
  const float* We1   = (const float*)d_in[7];
  const float* att1  = (const float*)d_in[8];
  const float* bias1 = (const float*)d_in[9];
  const float* Wl2   = (const float*)d_in[10];
  const float* bl2   = (const float*)d_in[11];
  const float* Wr2   = (const float*)d_in[12];
  const float* br2   = (const float*)d_in[13];
  const float* We2   = (const float*)d_in[14];
  const float* att2  = (const float*)d_in[15];
  const float* bias2 = (const float*)d_in[16];
  const float* w_ln1 = (const float*)d_in[17];
  const float* w_ln3 = (const float*)d_in[18];
  const float* W_out = (const float*)d_in[19];
  float* out = (float*)d_out;
  (void)in_sizes; (void)n_in; (void)out_size; (void)ws_size;

  const int* src = ei;
  const int* dst = ei + NE;

  char* wsp = (char*)d_ws;
  auto alloc = [&](size_t nbytes) {
    char* ptr = wsp;
    wsp += ((nbytes + 255) / 256) * 256;
    return ptr;
  };
  int*   cnti   = (int*)  alloc((size_t)NN * 4);   // zeroed by k_cast (int4 stores)
  int2*  se     = (int2*) alloc((size_t)NN * CAP * 8);   // padded CSR (15.4 MB)
  unsigned short* xb   = (unsigned short*)alloc((size_t)NN * D2 * 2);
  unsigned short* Wc1  = (unsigned short*)alloc((size_t)2 * D1 * D2 * 2);
  unsigned short* Wc2  = (unsigned short*)alloc((size_t)2 * D2 * D1 * 2);
  unsigned short* xl1  = (unsigned short*)alloc((size_t)NN * D1 * 2);  // gather table
  unsigned short* xr1  = (unsigned short*)alloc((size_t)NN * D1 * 2);
  unsigned short* h1b  = (unsigned short*)alloc((size_t)NN * D1 * 2);
  unsigned short* xl2  = (unsigned short*)alloc((size_t)NN * D2 * 2);
  unsigned short* xr2  = (unsigned short*)alloc((size_t)NN * D2 * 2);

  // --- preamble: cast + cnti-zero (one kernel; no memset dispatch) ---
  k_cast<<<(KC_TOT + 255) / 256, 256, 0, stream>>>(
      x, Wl1, Wr1, Wl2, Wr2, cnti, xb, Wc1, Wc2);

  const int GB = NN / 4;             // 4 nodes/block, 1 wave each (NN % 4 == 0)
  // XCD-clustered 1D grids: 30 row-groups x 8 xcd-slots x NBN col-tiles
  const int G1 = 30 * 8 * 8;         // gemm1: NBN=8 -> 1920 (40 dead)
  const int G2 = 30 * 8 * 2;         // gemm2: NBN=2 -> 480  (10 dead)

  // --- layer 1 (fat): CSR scatter blocks [0,CSRB) + gemm blocks behind ---
  gemm_mfma<128, 4, 64, 8><<<CSRB + G1, 256, 0, stream>>>(
      xb, Wc1, bl1, br1, D1, xl1, xr1, NN, 2 * D1, D2,
      CSRB, src, dst, eattr, cnti, se);
  k_gat_node<D1, 4, true, true, false><<<GB, 256, 0, stream>>>(
      se, cnti, xl1, xr1, We1, att1, bias1, w_ln1, nullptr, h1b, nullptr);

  // --- layer 2: [xl2|xr2] = h1 @ [Wl2;Wr2]^T + [bl2;br2]  (split bf16 out) ---
  gemm_mfma<128, 4, 64, 2><<<G2, 256, 0, stream>>>(
      h1b, Wc2, bl2, br2, D2, xl2, xr2, NN, 2 * D2, D1,
      0, src, dst, eattr, cnti, se);
  k_gat_node<D2, 8, false, false, true><<<GB, 256, 0, stream>>>(
      se, cnti, xl2, xr2, We2, att2, bias2, w_ln3, W_out, nullptr, out);
}